// Round 8
// baseline (3743.683 us; speedup 1.0000x reference)
//
#include <hip/hip_runtime.h>

typedef unsigned short u16;
typedef unsigned int u32;
typedef unsigned long long u64;
typedef __attribute__((ext_vector_type(8))) short bf16x8;
typedef __attribute__((ext_vector_type(4))) float f32x4;
typedef __attribute__((ext_vector_type(8))) unsigned short u16x8;
typedef __attribute__((ext_vector_type(4))) unsigned short u16x4;

#define MFMA16(a, b, c) __builtin_amdgcn_mfma_f32_16x16x32_bf16(a, b, c, 0, 0, 0)

__device__ __forceinline__ u16 f2b(float f) {
    u32 u = __builtin_bit_cast(u32, f);
    u32 r = (u + 0x7fffu + ((u >> 16) & 1u)) >> 16;
    return (u16)r;
}
__device__ __forceinline__ float b2f(u16 h) {
    u32 u = ((u32)h) << 16;
    return __builtin_bit_cast(float, u);
}
__device__ __forceinline__ float sigm(float x) { return 1.0f / (1.0f + __expf(-x)); }
__device__ __forceinline__ float tanh_fast(float x) { return 1.0f - 2.0f / (__expf(2.0f * x) + 1.0f); }

// sc1 (MALL-coherent) agent-scope relaxed atomics.
// THIS ROUND: flag-free dataflow sync. hex slots are write-once, each 8B
// piece is one aligned atomic astore64, and real bf16 h values can never be
// 0xFFFF (NaN encoding; f2b of finite gate outputs is finite). So hex is
// pre-memset to 0xFF and consumers POLL THE DATA ITSELF via sc1 loads: a
// 16B chunk is ready when neither u64 half is all-ones. Removes per step:
// both __syncthreads, the pre-publish vmcnt drain, the flag store, and the
// flag poll round-trip. Waves free-run; only true dataflow waits remain.
// No circular waits => no deadlock (step s needs only step s-1 data).
__device__ __forceinline__ u64 aload64(const void* p) {
    return __hip_atomic_load((const u64*)p, __ATOMIC_RELAXED, __HIP_MEMORY_SCOPE_AGENT);
}
__device__ __forceinline__ void astore64(void* p, u64 v) {
    __hip_atomic_store((u64*)p, v, __ATOMIC_RELAXED, __HIP_MEMORY_SCOPE_AGENT);
}

// ---------------------------------------------------------------------------
// Embedding gather + f32->bf16 cast, time-major output x[t*64+b][e]
__global__ __launch_bounds__(256) void embed_k(const int* __restrict__ enc,
                                               const float* __restrict__ emb,
                                               u16* __restrict__ xb) {
    int idx = (blockIdx.x * 256 + threadIdx.x) * 4;
    int row = idx >> 9;
    int e = idx & 511;
    int t = row >> 6, b = row & 63;
    int tok = enc[b * 256 + t];
    const float4 v = *(const float4*)(emb + (size_t)tok * 512 + e);
    u16x4 o;
    o.x = f2b(v.x); o.y = f2b(v.y); o.z = f2b(v.z); o.w = f2b(v.w);
    *(u16x4*)(xb + idx) = o;
}

// Mask words: maskw[t] bit b = (enc[b][t] != 0)
__global__ void mask_k(const int* __restrict__ enc, u64* __restrict__ mw) {
    int t = threadIdx.x;
    u64 m = 0;
#pragma unroll 8
    for (int b = 0; b < 64; ++b)
        if (enc[b * 256 + t] != 0) m |= (1ull << b);
    mw[t] = m;
}

// ---------------------------------------------------------------------------
// Cast f32 [K][N] -> bf16 transposed [N][K] via LDS tile
__global__ __launch_bounds__(256) void castT_k(const float* __restrict__ src,
                                               u16* __restrict__ dst, int K, int N) {
    __shared__ float tile[64][65];
    int n0 = blockIdx.x * 64, k0 = blockIdx.y * 64;
    int tid = threadIdx.x;
#pragma unroll
    for (int it = 0; it < 4; ++it) {
        int e = tid + it * 256;
        int kk = e >> 4;
        int nn = (e & 15) * 4;
        const float4 v = *(const float4*)(src + (size_t)(k0 + kk) * N + n0 + nn);
        tile[kk][nn] = v.x; tile[kk][nn + 1] = v.y;
        tile[kk][nn + 2] = v.z; tile[kk][nn + 3] = v.w;
    }
    __syncthreads();
#pragma unroll
    for (int it = 0; it < 2; ++it) {
        int e = tid + it * 256;
        int nn = e >> 3;
        int ks = (e & 7) * 8;
        u16x8 o;
#pragma unroll
        for (int j = 0; j < 8; ++j) o[j] = f2b(tile[ks + j][nn]);
        *(u16x8*)(dst + (size_t)(n0 + nn) * K + k0 + ks) = o;
    }
}

// ---------------------------------------------------------------------------
// bf16 MFMA GEMM: zx = A[16384][Ak] @ Bt^T + bias, output laid out as
// zx[t][grp][2048 cols][16 b] (group slices cache-line-contiguous).
__global__ __launch_bounds__(256) void gemm_bias_k(
    const u16* __restrict__ A, int Ak,
    const u16* __restrict__ BtF, const u16* __restrict__ BtB,
    const float* __restrict__ biasF, const float* __restrict__ biasB,
    u16* __restrict__ outF, u16* __restrict__ outB) {
    const int dir = blockIdx.z;
    const u16* __restrict__ Bt = dir ? BtB : BtF;
    const float* __restrict__ bias = dir ? biasB : biasF;
    u16* __restrict__ out = dir ? outB : outF;

    const int m0 = blockIdx.y * 128, n0 = blockIdx.x * 128;
    __shared__ __align__(16) u16 As[128 * 40];
    __shared__ __align__(16) u16 Bs[128 * 40];
    const int tid = threadIdx.x;
    const int lane = tid & 63, w = tid >> 6;
    const int l15 = lane & 15, quad = lane >> 4;
    const int rb = (w >> 1) * 64, cb = (w & 1) * 64;

    f32x4 acc[4][4];
#pragma unroll
    for (int i = 0; i < 4; ++i)
#pragma unroll
        for (int j = 0; j < 4; ++j) acc[i][j] = (f32x4){0.f, 0.f, 0.f, 0.f};

    const int nkt = Ak >> 5;
    for (int kt = 0; kt < nkt; ++kt) {
        __syncthreads();
#pragma unroll
        for (int it = 0; it < 2; ++it) {
            int s = tid + it * 256;
            int r = s >> 2, seg = s & 3;
            *(uint4*)&As[r * 40 + seg * 8] =
                *(const uint4*)&A[(size_t)(m0 + r) * Ak + kt * 32 + seg * 8];
            *(uint4*)&Bs[r * 40 + seg * 8] =
                *(const uint4*)&Bt[(size_t)(n0 + r) * Ak + kt * 32 + seg * 8];
        }
        __syncthreads();
        bf16x8 af[4], bfr[4];
#pragma unroll
        for (int i = 0; i < 4; ++i)
            af[i] = *(const bf16x8*)&As[(rb + i * 16 + l15) * 40 + quad * 8];
#pragma unroll
        for (int j = 0; j < 4; ++j)
            bfr[j] = *(const bf16x8*)&Bs[(cb + j * 16 + l15) * 40 + quad * 8];
#pragma unroll
        for (int i = 0; i < 4; ++i)
#pragma unroll
            for (int j = 0; j < 4; ++j) acc[i][j] = MFMA16(af[i], bfr[j], acc[i][j]);
    }
#pragma unroll
    for (int j = 0; j < 4; ++j) {
        int col = n0 + cb + j * 16 + l15;
        float bv = bias[col];
#pragma unroll
        for (int i = 0; i < 4; ++i) {
            int m = m0 + rb + i * 16 + quad * 4;
            int t = m >> 6, b0 = m & 63;
            int grp = b0 >> 4, bi = b0 & 15;
            u16x4 o;
#pragma unroll
            for (int r = 0; r < 4; ++r) o[r] = f2b(acc[i][j][r] + bv);
            *(u16x4*)&out[(((size_t)t * 4 + grp) * 2048 + col) * 16 + bi] = o;
        }
    }
}

// ---------------------------------------------------------------------------
// Persistent bidirectional LSTM recurrence, FLAG-FREE dataflow sync.
// Partition: 2 dirs x 4 batch-groups of 16 x 16 WGs (32 units each).
// Per wave per step (waves fully independent, no barriers, no flags):
//   1. sentinel-poll (sc1) the 16 h chunks of step s-1 until valid
//   2. 32 MFMA + gates
//   3. sc1 8B h stores into hex[t] (write-once slot; store IS the publish)
//   4. out2 stores + next zx prefetch
// hex is pre-memset to 0xFF by the host launch; a chunk's u64 half equal to
// all-ones means "not yet written" (real bf16 h can never be 0xFFFF = NaN).
// hex[256][64][1024] doubles as out1 for layer 1.
__global__ __launch_bounds__(256, 1) void lstm_rec_k(
    const u16* __restrict__ zxF, const u16* __restrict__ zxB,  // [256][4][2048][16]
    const u16* __restrict__ UtF, const u16* __restrict__ UtB,  // [2048][512]
    const u64* __restrict__ maskw,
    u16* __restrict__ hex,     // [256][64][1024] write-once h history (=out1 for layer 1)
    float* __restrict__ out2,  // layer 2: d_out
    int layer) {
    const int wg = blockIdx.x;
    const int dir = wg >> 6;
    const int grp = (wg >> 4) & 3;   // batch group (16 rows)
    const int wu = wg & 15;          // unit block (32 units)
    const u16* __restrict__ zx = dir ? zxB : zxF;
    const u16* __restrict__ Ut = dir ? UtB : UtF;

    const int tid = threadIdx.x;
    const int lane = tid & 63, w = tid >> 6;
    const int l15 = lane & 15, quad = lane >> 4;
    const bool hi = (lane & 8) != 0;
    const int gc_l = (l15 >> 3) * 512 + wu * 32 + w * 8 + (l15 & 7);
    const int brow = grp * 16 + l15;        // h row this lane reads
    const int b0 = grp * 16 + quad * 4;     // batch base for acc rows
    const int bi0 = quad * 4;               // batch-in-group base for zx reads
    const int u = wu * 32 + w * 8 + (lane & 7);  // unit for stores

    // Preload U fragments: 2 N-tiles x 16 K-chunks (VGPR/AGPR-resident)
    bf16x8 bfr[2][16];
#pragma unroll
    for (int nt = 0; nt < 2; ++nt)
#pragma unroll
        for (int kt = 0; kt < 16; ++kt)
            bfr[nt][kt] = *(const bf16x8*)&Ut[(size_t)(nt * 1024 + gc_l) * 512 + kt * 32 + quad * 8];

    float hreg[4] = {0.f, 0.f, 0.f, 0.f};
    float creg[4] = {0.f, 0.f, 0.f, 0.f};

    // initial zx prefetch (t of step 0)
    int t0 = dir ? 255 : 0;
    u16x4 pz0 = *(const u16x4*)&zx[(((size_t)t0 * 4 + grp) * 2048 + gc_l) * 16 + bi0];
    u16x4 pz1 = *(const u16x4*)&zx[(((size_t)t0 * 4 + grp) * 2048 + 1024 + gc_l) * 16 + bi0];

    union HU { u64 q[2]; bf16x8 v; };

    for (int s = 0; s < 256; ++s) {
        const int t = dir ? (255 - s) : s;
        const int tp = dir ? (t + 1) : (t - 1);  // history slot to consume (s>0)

        const u64 mw = maskw[t];

        f32x4 acc0, acc1;
#pragma unroll
        for (int r = 0; r < 4; ++r) { acc0[r] = b2f(pz0[r]); acc1[r] = b2f(pz1[r]); }

        if (s) {
            // sentinel-poll the h_{t'} chunks (sc1 -> MALL, sees remote
            // producers). Chunk kt = units [kt*32 + quad*8, +8) of row brow,
            // written as two atomic 8B stores by producer WG kt, wave quad.
            const u16* hbase = hex + ((size_t)tp * 64 + brow) * 1024 + dir * 512 + quad * 8;
            HU hu[16];
            u32 inval = 0xffffu;
            while (true) {
#pragma unroll
                for (int kt = 0; kt < 16; ++kt)
                    if (inval & (1u << kt)) {
                        hu[kt].q[0] = aload64(hbase + kt * 32);
                        hu[kt].q[1] = aload64(hbase + kt * 32 + 4);
                    }
                u32 ni = 0;
#pragma unroll
                for (int kt = 0; kt < 16; ++kt)
                    if ((inval & (1u << kt)) &&
                        (hu[kt].q[0] == ~0ull || hu[kt].q[1] == ~0ull))
                        ni |= 1u << kt;
                inval = ni;
                if (!__ballot(inval != 0u)) break;
            }
#pragma unroll
            for (int kt = 0; kt < 16; ++kt) {
                acc0 = MFMA16(hu[kt].v, bfr[0][kt], acc0);
                acc1 = MFMA16(hu[kt].v, bfr[1][kt], acc1);
            }
        }

#pragma unroll
        for (int r = 0; r < 4; ++r) {
            int b = b0 + r;
            float z0 = acc0[r], z1 = acc1[r];
            float p0 = __shfl_xor(z0, 8);
            float p1 = __shfl_xor(z1, 8);
            float iz = hi ? p0 : z0, fz = hi ? z0 : p0;
            float gz = hi ? p1 : z1, oz = hi ? z1 : p1;
            float i_ = sigm(iz), f_ = sigm(fz), g_ = tanh_fast(gz), o_ = sigm(oz);
            float cn = f_ * creg[r] + i_ * g_;
            float hv = o_ * tanh_fast(cn);
            if (!((mw >> b) & 1ull)) { cn = creg[r]; hv = hreg[r]; }
            creg[r] = cn; hreg[r] = hv;
            if (!hi) {
                u16 hb = f2b(hv);
                // pack (u..u+3) into u64; lane&3==0 stores 8B (u === 0 mod 4).
                // This atomic sc1 store IS the publication (and the out1
                // store for layer 1). No drain, no flag, no barrier.
                u32 pair = (u32)hb | (((u32)(u16)__shfl_xor((int)(u32)hb, 1)) << 16);
                u64 q = (u64)pair | ((u64)(u32)__shfl_xor((int)pair, 2) << 32);
                if (!(lane & 3))
                    astore64(&hex[((size_t)t * 64 + b) * 1024 + dir * 512 + u], q);
            }
        }

        // post-publish: layer-2 output stores + next-step zx prefetch overlap
        // the next step's poll.
        if (layer == 2 && !hi) {
#pragma unroll
            for (int r = 0; r < 4; ++r) {
                u32 h32 = __builtin_bit_cast(u32, hreg[r]);
                u32 ot = (u32)__shfl_xor((int)h32, 1);
                if (!(lane & 1)) {
                    u64 qq = (u64)h32 | ((u64)ot << 32);
                    *(u64*)&out2[(size_t)(b0 + r) * 262144 + (size_t)t * 1024 + dir * 512 + u] = qq;
                }
            }
            if (s == 255) {
#pragma unroll
                for (int r = 0; r < 4; ++r) {
                    int b = b0 + r;
                    out2[16777216 + b * 1024 + dir * 512 + u] = hreg[r];
                    out2[16777216 + 65536 + b * 1024 + dir * 512 + u] = creg[r];
                }
            }
        }
        {
            int tn = dir ? (s < 255 ? 254 - s : 0) : (s < 255 ? s + 1 : 255);
            pz0 = *(const u16x4*)&zx[(((size_t)tn * 4 + grp) * 2048 + gc_l) * 16 + bi0];
            pz1 = *(const u16x4*)&zx[(((size_t)tn * 4 + grp) * 2048 + 1024 + gc_l) * 16 + bi0];
        }
    }
}

// ---------------------------------------------------------------------------
extern "C" void kernel_launch(void* const* d_in, const int* in_sizes, int n_in,
                              void* d_out, int out_size, void* d_ws, size_t ws_size,
                              hipStream_t stream) {
    const int* enc = (const int*)d_in[0];
    const float* emb = (const float*)d_in[1];
    const float* W1f = (const float*)d_in[2];
    const float* U1f = (const float*)d_in[3];
    const float* b1f = (const float*)d_in[4];
    const float* W1b = (const float*)d_in[5];
    const float* U1b = (const float*)d_in[6];
    const float* b1b = (const float*)d_in[7];
    const float* W2f = (const float*)d_in[8];
    const float* U2f = (const float*)d_in[9];
    const float* b2f = (const float*)d_in[10];
    const float* W2b = (const float*)d_in[11];
    const float* U2b = (const float*)d_in[12];
    const float* b2b = (const float*)d_in[13];

    char* ws = (char*)d_ws;
    constexpr size_t ZXF = 0;                      // 67,108,864  bf16 [256][4][2048][16]
    constexpr size_t ZXB = 67108864;               // 67,108,864
    constexpr size_t XB = 134217728;               // 16,777,216  bf16 [16384][512]
    constexpr size_t OUT1 = 150994944;             // 33,554,432  bf16 [256][64][1024] = h history
    constexpr size_t WT = 184549376;               // 20,971,520 packed bf16 transposed weights
    constexpr size_t W1FT = WT + 0;
    constexpr size_t W1BT = WT + 2097152;
    constexpr size_t U1FT = WT + 4194304;
    constexpr size_t U1BT = WT + 6291456;
    constexpr size_t W2FT = WT + 8388608;
    constexpr size_t W2BT = WT + 12582912;
    constexpr size_t U2FT = WT + 16777216;
    constexpr size_t U2BT = WT + 18874368;
    constexpr size_t MASKW = 205520896 + 4096;     // 2048 bytes

    u16* zxF = (u16*)(ws + ZXF);
    u16* zxB = (u16*)(ws + ZXB);
    u16* xb = (u16*)(ws + XB);
    u16* out1 = (u16*)(ws + OUT1);
    u64* maskw = (u64*)(ws + MASKW);

    // sentinel-init the h history: 0xFF bytes = u64 all-ones = "unwritten".
    // (ws poison is 0xAA, which would read as VALID -- this memset is load-
    // bearing for correctness.)
    hipMemsetAsync(ws + OUT1, 0xFF, 33554432, stream);

    embed_k<<<8192, 256, 0, stream>>>(enc, emb, xb);
    mask_k<<<1, 256, 0, stream>>>(enc, maskw);

    castT_k<<<dim3(32, 8), 256, 0, stream>>>(W1f, (u16*)(ws + W1FT), 512, 2048);
    castT_k<<<dim3(32, 8), 256, 0, stream>>>(W1b, (u16*)(ws + W1BT), 512, 2048);
    castT_k<<<dim3(32, 8), 256, 0, stream>>>(U1f, (u16*)(ws + U1FT), 512, 2048);
    castT_k<<<dim3(32, 8), 256, 0, stream>>>(U1b, (u16*)(ws + U1BT), 512, 2048);
    castT_k<<<dim3(32, 16), 256, 0, stream>>>(W2f, (u16*)(ws + W2FT), 1024, 2048);
    castT_k<<<dim3(32, 16), 256, 0, stream>>>(W2b, (u16*)(ws + W2BT), 1024, 2048);
    castT_k<<<dim3(32, 8), 256, 0, stream>>>(U2f, (u16*)(ws + U2FT), 512, 2048);
    castT_k<<<dim3(32, 8), 256, 0, stream>>>(U2b, (u16*)(ws + U2BT), 512, 2048);

    gemm_bias_k<<<dim3(16, 128, 2), 256, 0, stream>>>(
        xb, 512, (u16*)(ws + W1FT), (u16*)(ws + W1BT), b1f, b1b, zxF, zxB);
    // layer-1 recurrence: h history IS out1 (write-once, data = ready signal)
    lstm_rec_k<<<128, 256, 0, stream>>>(
        zxF, zxB, (u16*)(ws + U1FT), (u16*)(ws + U1BT), maskw,
        out1, nullptr, 1);

    gemm_bias_k<<<dim3(16, 128, 2), 256, 0, stream>>>(
        out1, 1024, (u16*)(ws + W2FT), (u16*)(ws + W2BT), b2f, b2b, zxF, zxB);
    // re-init sentinel for layer 2 (stream-ordered AFTER gemm2 consumed out1)
    hipMemsetAsync(ws + OUT1, 0xFF, 33554432, stream);
    // layer-2 recurrence: reuse the (now dead) out1 region as its h history
    lstm_rec_k<<<128, 256, 0, stream>>>(
        zxF, zxB, (u16*)(ws + U2FT), (u16*)(ws + U2BT), maskw,
        out1, (float*)d_out, 2);
}

// Round 9
// 2748.760 us; speedup vs baseline: 1.3620x; 1.3620x over previous
//
#include <hip/hip_runtime.h>

typedef unsigned short u16;
typedef unsigned int u32;
typedef unsigned long long u64;
typedef __attribute__((ext_vector_type(8))) short bf16x8;
typedef __attribute__((ext_vector_type(4))) float f32x4;
typedef __attribute__((ext_vector_type(8))) unsigned short u16x8;
typedef __attribute__((ext_vector_type(4))) unsigned short u16x4;

#define MFMA16(a, b, c) __builtin_amdgcn_mfma_f32_16x16x32_bf16(a, b, c, 0, 0, 0)

__device__ __forceinline__ u16 f2b(float f) {
    u32 u = __builtin_bit_cast(u32, f);
    u32 r = (u + 0x7fffu + ((u >> 16) & 1u)) >> 16;
    return (u16)r;
}
__device__ __forceinline__ float b2f(u16 h) {
    u32 u = ((u32)h) << 16;
    return __builtin_bit_cast(float, u);
}
__device__ __forceinline__ float sigm(float x) { return 1.0f / (1.0f + __expf(-x)); }
__device__ __forceinline__ float tanh_fast(float x) { return 1.0f - 2.0f / (__expf(2.0f * x) + 1.0f); }

// sc1 (MALL-coherent) agent-scope relaxed atomics: h PUBLISHING and flags.
// h CONSUMPTION is plain cached loads (write-once history + dispatch-boundary
// invalidation => never stale). r3 protocol, proven best (1230us/dispatch).
// Falsified alternatives: per-wave flags (r1), full-line publish (r4), 16B
// publish (r7), flag-free data polling (r8: sc1 sentinel re-reads bypass L2
// -> +68MB FETCH, +36% time).
// THIS ROUND: XCD-affinity remap only. sys = wg & 7 (was wg >> 4) so under
// round-robin blockIdx%8 -> XCD dispatch, all 16 WGs of a system share ONE
// XCD: shared-L2 h fills (1 MALL fill per line instead of 8), die-local flag
// propagation, intra-die straggler jitter. Pure index change; protocol and
// instruction stream otherwise identical to r3.
__device__ __forceinline__ u32 aload32(const void* p) {
    return __hip_atomic_load((const u32*)p, __ATOMIC_RELAXED, __HIP_MEMORY_SCOPE_AGENT);
}
__device__ __forceinline__ void astore32(void* p, u32 v) {
    __hip_atomic_store((u32*)p, v, __ATOMIC_RELAXED, __HIP_MEMORY_SCOPE_AGENT);
}
__device__ __forceinline__ void astore64(void* p, u64 v) {
    __hip_atomic_store((u64*)p, v, __ATOMIC_RELAXED, __HIP_MEMORY_SCOPE_AGENT);
}

// ---------------------------------------------------------------------------
// Embedding gather + f32->bf16 cast, time-major output x[t*64+b][e]
__global__ __launch_bounds__(256) void embed_k(const int* __restrict__ enc,
                                               const float* __restrict__ emb,
                                               u16* __restrict__ xb) {
    int idx = (blockIdx.x * 256 + threadIdx.x) * 4;
    int row = idx >> 9;
    int e = idx & 511;
    int t = row >> 6, b = row & 63;
    int tok = enc[b * 256 + t];
    const float4 v = *(const float4*)(emb + (size_t)tok * 512 + e);
    u16x4 o;
    o.x = f2b(v.x); o.y = f2b(v.y); o.z = f2b(v.z); o.w = f2b(v.w);
    *(u16x4*)(xb + idx) = o;
}

// Mask words: maskw[t] bit b = (enc[b][t] != 0)
__global__ void mask_k(const int* __restrict__ enc, u64* __restrict__ mw) {
    int t = threadIdx.x;
    u64 m = 0;
#pragma unroll 8
    for (int b = 0; b < 64; ++b)
        if (enc[b * 256 + t] != 0) m |= (1ull << b);
    mw[t] = m;
}

// ---------------------------------------------------------------------------
// Cast f32 [K][N] -> bf16 transposed [N][K] via LDS tile
__global__ __launch_bounds__(256) void castT_k(const float* __restrict__ src,
                                               u16* __restrict__ dst, int K, int N) {
    __shared__ float tile[64][65];
    int n0 = blockIdx.x * 64, k0 = blockIdx.y * 64;
    int tid = threadIdx.x;
#pragma unroll
    for (int it = 0; it < 4; ++it) {
        int e = tid + it * 256;
        int kk = e >> 4;
        int nn = (e & 15) * 4;
        const float4 v = *(const float4*)(src + (size_t)(k0 + kk) * N + n0 + nn);
        tile[kk][nn] = v.x; tile[kk][nn + 1] = v.y;
        tile[kk][nn + 2] = v.z; tile[kk][nn + 3] = v.w;
    }
    __syncthreads();
#pragma unroll
    for (int it = 0; it < 2; ++it) {
        int e = tid + it * 256;
        int nn = e >> 3;
        int ks = (e & 7) * 8;
        u16x8 o;
#pragma unroll
        for (int j = 0; j < 8; ++j) o[j] = f2b(tile[ks + j][nn]);
        *(u16x8*)(dst + (size_t)(n0 + nn) * K + k0 + ks) = o;
    }
}

// ---------------------------------------------------------------------------
// bf16 MFMA GEMM: zx = A[16384][Ak] @ Bt^T + bias, output laid out as
// zx[t][grp][2048 cols][16 b] (group slices cache-line-contiguous).
__global__ __launch_bounds__(256) void gemm_bias_k(
    const u16* __restrict__ A, int Ak,
    const u16* __restrict__ BtF, const u16* __restrict__ BtB,
    const float* __restrict__ biasF, const float* __restrict__ biasB,
    u16* __restrict__ outF, u16* __restrict__ outB) {
    const int dir = blockIdx.z;
    const u16* __restrict__ Bt = dir ? BtB : BtF;
    const float* __restrict__ bias = dir ? biasB : biasF;
    u16* __restrict__ out = dir ? outB : outF;

    const int m0 = blockIdx.y * 128, n0 = blockIdx.x * 128;
    __shared__ __align__(16) u16 As[128 * 40];
    __shared__ __align__(16) u16 Bs[128 * 40];
    const int tid = threadIdx.x;
    const int lane = tid & 63, w = tid >> 6;
    const int l15 = lane & 15, quad = lane >> 4;
    const int rb = (w >> 1) * 64, cb = (w & 1) * 64;

    f32x4 acc[4][4];
#pragma unroll
    for (int i = 0; i < 4; ++i)
#pragma unroll
        for (int j = 0; j < 4; ++j) acc[i][j] = (f32x4){0.f, 0.f, 0.f, 0.f};

    const int nkt = Ak >> 5;
    for (int kt = 0; kt < nkt; ++kt) {
        __syncthreads();
#pragma unroll
        for (int it = 0; it < 2; ++it) {
            int s = tid + it * 256;
            int r = s >> 2, seg = s & 3;
            *(uint4*)&As[r * 40 + seg * 8] =
                *(const uint4*)&A[(size_t)(m0 + r) * Ak + kt * 32 + seg * 8];
            *(uint4*)&Bs[r * 40 + seg * 8] =
                *(const uint4*)&Bt[(size_t)(n0 + r) * Ak + kt * 32 + seg * 8];
        }
        __syncthreads();
        bf16x8 af[4], bfr[4];
#pragma unroll
        for (int i = 0; i < 4; ++i)
            af[i] = *(const bf16x8*)&As[(rb + i * 16 + l15) * 40 + quad * 8];
#pragma unroll
        for (int j = 0; j < 4; ++j)
            bfr[j] = *(const bf16x8*)&Bs[(cb + j * 16 + l15) * 40 + quad * 8];
#pragma unroll
        for (int i = 0; i < 4; ++i)
#pragma unroll
            for (int j = 0; j < 4; ++j) acc[i][j] = MFMA16(af[i], bfr[j], acc[i][j]);
    }
#pragma unroll
    for (int j = 0; j < 4; ++j) {
        int col = n0 + cb + j * 16 + l15;
        float bv = bias[col];
#pragma unroll
        for (int i = 0; i < 4; ++i) {
            int m = m0 + rb + i * 16 + quad * 4;
            int t = m >> 6, b0 = m & 63;
            int grp = b0 >> 4, bi = b0 & 15;
            u16x4 o;
#pragma unroll
            for (int r = 0; r < 4; ++r) o[r] = f2b(acc[i][j][r] + bv);
            *(u16x4*)&out[(((size_t)t * 4 + grp) * 2048 + col) * 16 + bi] = o;
        }
    }
}

// ---------------------------------------------------------------------------
// Persistent bidirectional LSTM recurrence (r3 protocol) with XCD-AFFINE
// system decode: sys = wg & 7 (dir = sys>>2, grp = sys&3), wu = wg >> 3.
// Under round-robin blockIdx%8 -> XCD dispatch, each 16-WG system lives on
// one XCD: h lines fill one shared L2, flag hops are die-local.
// Per step: poll 16 flags (wave 0) -> __syncthreads -> cached h loads ->
// MFMA -> gates -> sc1 8B h stores -> __syncthreads (drains) -> flag=s+1 ->
// out2 stores + zx prefetch. hex[256][64][1024] doubles as out1 for layer 1.
__global__ __launch_bounds__(256, 1) void lstm_rec_k(
    const u16* __restrict__ zxF, const u16* __restrict__ zxB,  // [256][4][2048][16]
    const u16* __restrict__ UtF, const u16* __restrict__ UtB,  // [2048][512]
    const u64* __restrict__ maskw,
    u16* __restrict__ hex,     // [256][64][1024] write-once h history (=out1 for layer 1)
    u32* __restrict__ flgs,    // [8 sys][32] u32
    float* __restrict__ out2,  // layer 2: d_out
    int layer) {
    const int wg = blockIdx.x;
    const int sys = wg & 7;          // XCD-affine system id
    const int dir = sys >> 2;
    const int grp = sys & 3;         // batch group (16 rows)
    const int wu = wg >> 3;          // unit block (32 units), 0..15
    const u16* __restrict__ zx = dir ? zxB : zxF;
    const u16* __restrict__ Ut = dir ? UtB : UtF;
    u32* __restrict__ flg = flgs + sys * 32;

    const int tid = threadIdx.x;
    const int lane = tid & 63, w = tid >> 6;
    const int l15 = lane & 15, quad = lane >> 4;
    const bool hi = (lane & 8) != 0;
    const int gc_l = (l15 >> 3) * 512 + wu * 32 + w * 8 + (l15 & 7);
    const int brow = grp * 16 + l15;        // h row this lane reads
    const int b0 = grp * 16 + quad * 4;     // batch base for acc rows
    const int bi0 = quad * 4;               // batch-in-group base for zx reads
    const int u = wu * 32 + w * 8 + (lane & 7);  // unit for stores

    // Preload U fragments: 2 N-tiles x 16 K-chunks (VGPR/AGPR-resident)
    bf16x8 bfr[2][16];
#pragma unroll
    for (int nt = 0; nt < 2; ++nt)
#pragma unroll
        for (int kt = 0; kt < 16; ++kt)
            bfr[nt][kt] = *(const bf16x8*)&Ut[(size_t)(nt * 1024 + gc_l) * 512 + kt * 32 + quad * 8];

    float hreg[4] = {0.f, 0.f, 0.f, 0.f};
    float creg[4] = {0.f, 0.f, 0.f, 0.f};

    // initial zx prefetch (t of step 0)
    int t0 = dir ? 255 : 0;
    u16x4 pz0 = *(const u16x4*)&zx[(((size_t)t0 * 4 + grp) * 2048 + gc_l) * 16 + bi0];
    u16x4 pz1 = *(const u16x4*)&zx[(((size_t)t0 * 4 + grp) * 2048 + 1024 + gc_l) * 16 + bi0];

    for (int s = 0; s < 256; ++s) {
        const int t = dir ? (255 - s) : s;
        const int tp = dir ? (t + 1) : (t - 1);  // history slot to consume (s>0)

        // gate: wait until all 16 WGs of this system published step s.
        if (s) {
            if (tid < 16) {
                u32 v = aload32(&flg[tid]);
                while (__ballot(v < (u32)s)) v = aload32(&flg[tid]);
            }
            __syncthreads();
        }

        const u64 mw = maskw[t];

        f32x4 acc0, acc1;
#pragma unroll
        for (int r = 0; r < 4; ++r) { acc0[r] = b2f(pz0[r]); acc1[r] = b2f(pz1[r]); }

        if (s) {
            // h_{t'} slice for this group's 16 rows: plain cached 16B loads
            const u16* hbase = hex + ((size_t)tp * 64 + brow) * 1024 + dir * 512 + quad * 8;
            bf16x8 hfr[16];
#pragma unroll
            for (int kt = 0; kt < 16; ++kt) hfr[kt] = *(const bf16x8*)&hbase[kt * 32];
#pragma unroll
            for (int kt = 0; kt < 16; ++kt) {
                acc0 = MFMA16(hfr[kt], bfr[0][kt], acc0);
                acc1 = MFMA16(hfr[kt], bfr[1][kt], acc1);
            }
        }

#pragma unroll
        for (int r = 0; r < 4; ++r) {
            int b = b0 + r;
            float z0 = acc0[r], z1 = acc1[r];
            float p0 = __shfl_xor(z0, 8);
            float p1 = __shfl_xor(z1, 8);
            float iz = hi ? p0 : z0, fz = hi ? z0 : p0;
            float gz = hi ? p1 : z1, oz = hi ? z1 : p1;
            float i_ = sigm(iz), f_ = sigm(fz), g_ = tanh_fast(gz), o_ = sigm(oz);
            float cn = f_ * creg[r] + i_ * g_;
            float hv = o_ * tanh_fast(cn);
            if (!((mw >> b) & 1ull)) { cn = creg[r]; hv = hreg[r]; }
            creg[r] = cn; hreg[r] = hv;
            if (!hi) {
                u16 hb = f2b(hv);
                // pack (u..u+3) into u64; lane&3==0 stores 8B (u === 0 mod 4).
                // This sc1 store IS the out1 store for layer 1.
                u32 pair = (u32)hb | (((u32)(u16)__shfl_xor((int)(u32)hb, 1)) << 16);
                u64 q = (u64)pair | ((u64)(u32)__shfl_xor((int)pair, 2) << 32);
                if (!(lane & 3))
                    astore64(&hex[((size_t)t * 64 + b) * 1024 + dir * 512 + u], q);
            }
        }

        // drain h stores (compiler emits vmcnt(0) before s_barrier), publish
        __syncthreads();
        if (tid == 0) astore32(&flg[wu], (u32)(s + 1));

        // post-publish: layer-2 output stores + next-step zx prefetch overlap
        // the next gate's poll.
        if (layer == 2 && !hi) {
#pragma unroll
            for (int r = 0; r < 4; ++r) {
                u32 h32 = __builtin_bit_cast(u32, hreg[r]);
                u32 ot = (u32)__shfl_xor((int)h32, 1);
                if (!(lane & 1)) {
                    u64 qq = (u64)h32 | ((u64)ot << 32);
                    *(u64*)&out2[(size_t)(b0 + r) * 262144 + (size_t)t * 1024 + dir * 512 + u] = qq;
                }
            }
            if (s == 255) {
#pragma unroll
                for (int r = 0; r < 4; ++r) {
                    int b = b0 + r;
                    out2[16777216 + b * 1024 + dir * 512 + u] = hreg[r];
                    out2[16777216 + 65536 + b * 1024 + dir * 512 + u] = creg[r];
                }
            }
        }
        {
            int tn = dir ? (s < 255 ? 254 - s : 0) : (s < 255 ? s + 1 : 255);
            pz0 = *(const u16x4*)&zx[(((size_t)tn * 4 + grp) * 2048 + gc_l) * 16 + bi0];
            pz1 = *(const u16x4*)&zx[(((size_t)tn * 4 + grp) * 2048 + 1024 + gc_l) * 16 + bi0];
        }
    }
}

// ---------------------------------------------------------------------------
extern "C" void kernel_launch(void* const* d_in, const int* in_sizes, int n_in,
                              void* d_out, int out_size, void* d_ws, size_t ws_size,
                              hipStream_t stream) {
    const int* enc = (const int*)d_in[0];
    const float* emb = (const float*)d_in[1];
    const float* W1f = (const float*)d_in[2];
    const float* U1f = (const float*)d_in[3];
    const float* b1f = (const float*)d_in[4];
    const float* W1b = (const float*)d_in[5];
    const float* U1b = (const float*)d_in[6];
    const float* b1b = (const float*)d_in[7];
    const float* W2f = (const float*)d_in[8];
    const float* U2f = (const float*)d_in[9];
    const float* b2f = (const float*)d_in[10];
    const float* W2b = (const float*)d_in[11];
    const float* U2b = (const float*)d_in[12];
    const float* b2b = (const float*)d_in[13];

    char* ws = (char*)d_ws;
    constexpr size_t ZXF = 0;                      // 67,108,864  bf16 [256][4][2048][16]
    constexpr size_t ZXB = 67108864;               // 67,108,864
    constexpr size_t XB = 134217728;               // 16,777,216  bf16 [16384][512]
    constexpr size_t OUT1 = 150994944;             // 33,554,432  bf16 [256][64][1024] = h history
    constexpr size_t WT = 184549376;               // 20,971,520 packed bf16 transposed weights
    constexpr size_t W1FT = WT + 0;
    constexpr size_t W1BT = WT + 2097152;
    constexpr size_t U1FT = WT + 4194304;
    constexpr size_t U1BT = WT + 6291456;
    constexpr size_t W2FT = WT + 8388608;
    constexpr size_t W2BT = WT + 12582912;
    constexpr size_t U2FT = WT + 16777216;
    constexpr size_t U2BT = WT + 18874368;
    constexpr size_t FLG = 205520896;              // [8][32] u32 (reused per layer)
    constexpr size_t MASKW = FLG + 4096;           // 2048 bytes

    u16* zxF = (u16*)(ws + ZXF);
    u16* zxB = (u16*)(ws + ZXB);
    u16* xb = (u16*)(ws + XB);
    u16* out1 = (u16*)(ws + OUT1);
    u32* flgs = (u32*)(ws + FLG);
    u64* maskw = (u64*)(ws + MASKW);

    // zero flags (ws is poisoned 0xAA each launch)
    hipMemsetAsync(ws + FLG, 0, 4096, stream);

    embed_k<<<8192, 256, 0, stream>>>(enc, emb, xb);
    mask_k<<<1, 256, 0, stream>>>(enc, maskw);

    castT_k<<<dim3(32, 8), 256, 0, stream>>>(W1f, (u16*)(ws + W1FT), 512, 2048);
    castT_k<<<dim3(32, 8), 256, 0, stream>>>(W1b, (u16*)(ws + W1BT), 512, 2048);
    castT_k<<<dim3(32, 8), 256, 0, stream>>>(U1f, (u16*)(ws + U1FT), 512, 2048);
    castT_k<<<dim3(32, 8), 256, 0, stream>>>(U1b, (u16*)(ws + U1BT), 512, 2048);
    castT_k<<<dim3(32, 16), 256, 0, stream>>>(W2f, (u16*)(ws + W2FT), 1024, 2048);
    castT_k<<<dim3(32, 16), 256, 0, stream>>>(W2b, (u16*)(ws + W2BT), 1024, 2048);
    castT_k<<<dim3(32, 8), 256, 0, stream>>>(U2f, (u16*)(ws + U2FT), 512, 2048);
    castT_k<<<dim3(32, 8), 256, 0, stream>>>(U2b, (u16*)(ws + U2BT), 512, 2048);

    gemm_bias_k<<<dim3(16, 128, 2), 256, 0, stream>>>(
        xb, 512, (u16*)(ws + W1FT), (u16*)(ws + W1BT), b1f, b1b, zxF, zxB);
    // layer-1 recurrence: h history IS out1 (write-once, sc1-published)
    lstm_rec_k<<<128, 256, 0, stream>>>(
        zxF, zxB, (u16*)(ws + U1FT), (u16*)(ws + U1BT), maskw,
        out1, flgs, nullptr, 1);

    gemm_bias_k<<<dim3(16, 128, 2), 256, 0, stream>>>(
        out1, 1024, (u16*)(ws + W2FT), (u16*)(ws + W2BT), b2f, b2b, zxF, zxB);
    // re-zero flags for layer 2 (stream-ordered after rec1)
    hipMemsetAsync(ws + FLG, 0, 4096, stream);
    // layer-2 recurrence: reuse the (now dead) out1 region as its h history
    lstm_rec_k<<<128, 256, 0, stream>>>(
        zxF, zxB, (u16*)(ws + U2FT), (u16*)(ws + U2BT), maskw,
        out1, flgs, (float*)d_out, 2);
}